// Round 11
// baseline (77.936 us; speedup 1.0000x reference)
//
#include <hip/hip_runtime.h>

#define BB 32
#define NN 1024
#define MM 1024
#define DD 128

typedef __attribute__((ext_vector_type(4))) float f32x4;
typedef __attribute__((ext_vector_type(8))) __bf16 bf16x8;
typedef unsigned short ushort_t;
typedef unsigned int uint_t;

#define L2E 1.44269504f
#define KEXP 9.357623e-14f      // exp(-30): folded softmax shift
#define KEXPINV 1.0686475e13f   // exp(+30)

__device__ __forceinline__ unsigned f2bf(float x) {
    unsigned u = __builtin_bit_cast(unsigned, x);
    return (u + 0x7fffu + ((u >> 16) & 1u)) >> 16;  // RNE bf16, finite inputs
}

// ---- Kernel 1 (prep): gq = bf16(g)^T tiles ; e2 = g·a2 ; e1 = h·a1 ----------
__global__ __launch_bounds__(256) void prep(
    const float* __restrict__ g, const float* __restrict__ h,
    const float* __restrict__ a1, const float* __restrict__ a2,
    ushort_t* __restrict__ gq, float* __restrict__ e1, float* __restrict__ e2)
{
    __shared__ ushort_t tl[DD][66];  // +2 pad breaks write bank conflicts
    int b = blockIdx.y, m0 = blockIdx.x * 64, t = threadIdx.x;

    #pragma unroll
    for (int i = 0; i < 8; i++) {
        int idx = i * 256 + t;
        int m = idx >> 5;            // 32 consecutive lanes share row m
        int c4 = (idx & 31) * 4;
        float4 v = *(const float4*)(h + ((size_t)(b * NN + m0 + m)) * DD + c4);
        float4 av = *(const float4*)(a1 + c4);
        float p = v.x * av.x + v.y * av.y + v.z * av.z + v.w * av.w;
        #pragma unroll
        for (int s = 16; s; s >>= 1) p += __shfl_xor(p, s);
        if ((t & 31) == 0) e1[b * NN + m0 + m] = p;
    }
    #pragma unroll
    for (int i = 0; i < 8; i++) {
        int idx = i * 256 + t;
        int m = idx >> 5;
        int c4 = (idx & 31) * 4;
        float4 v = *(const float4*)(g + ((size_t)(b * MM + m0 + m)) * DD + c4);
        tl[c4 + 0][m] = (ushort_t)f2bf(v.x);
        tl[c4 + 1][m] = (ushort_t)f2bf(v.y);
        tl[c4 + 2][m] = (ushort_t)f2bf(v.z);
        tl[c4 + 3][m] = (ushort_t)f2bf(v.w);
        float4 av = *(const float4*)(a2 + c4);
        float p = v.x * av.x + v.y * av.y + v.z * av.z + v.w * av.w;
        #pragma unroll
        for (int s = 16; s; s >>= 1) p += __shfl_xor(p, s);
        if ((t & 31) == 0) e2[b * MM + m0 + m] = p;
    }
    __syncthreads();
    #pragma unroll
    for (int i = 0; i < 4; i++) {
        int idx = i * 256 + t;
        int d = idx >> 3;            // 0..127
        int c = (idx & 7) * 8;       // local m group
        int4 o;
        o.x = (int)((unsigned)tl[d][c + 0] | ((unsigned)tl[d][c + 1] << 16));
        o.y = (int)((unsigned)tl[d][c + 2] | ((unsigned)tl[d][c + 3] << 16));
        o.z = (int)((unsigned)tl[d][c + 4] | ((unsigned)tl[d][c + 5] << 16));
        o.w = (int)((unsigned)tl[d][c + 6] | ((unsigned)tl[d][c + 7] << 16));
        int mg = m0 + c;
        *(int4*)(gq + (((size_t)((b * 32 + (mg >> 5)) * DD + d)) << 5) + (mg & 31)) = o;
    }
}

// ---- Kernel 2: fused adj-stream + softmax + PV, explicit T3+T4 pipeline -----
// block = 4 waves (wr x wd): wave = 16 rows x 64 d. grid 1024 = 4 blocks/CU.
// Register FIFO, depth 2 for adj and gq; region = 6 VMEM ops; wait vmcnt(6)
// at each iter top => chunks mc..mc+1 always in flight (~12 KB/wave).
__global__ __launch_bounds__(256, 4) void attn_fused(
    const int* __restrict__ adj, const ushort_t* __restrict__ gq,
    const float* __restrict__ e1, const float* __restrict__ e2,
    float* __restrict__ out)
{
    __shared__ __align__(16) float e2S[MM];
    int b = blockIdx.y, n0 = blockIdx.x * 32, t = threadIdx.x;
    int wid = t >> 6, lane = t & 63;
    int wr = wid >> 1, wd = wid & 1;
    int rlo = lane & 15, hh = lane >> 4;
    int row = n0 + wr * 16 + rlo;

    {
        float4 ev = *(const float4*)(e2 + b * MM + t * 4);
        ev.x *= L2E; ev.y *= L2E; ev.z *= L2E; ev.w *= L2E;
        *(float4*)(&e2S[t * 4]) = ev;
    }
    __syncthreads();

    float e1f = L2E * e1[b * NN + row];

    const int* ap = adj + (size_t)(b * NN + row) * MM + 8 * hh;
    const ushort_t* gb = gq + (size_t)b * (32 * DD * 32)
                       + wd * 2048 + rlo * 32 + 8 * hh;

    f32x4 acc0 = {0.f,0.f,0.f,0.f}, acc1 = {0.f,0.f,0.f,0.f};
    f32x4 acc2 = {0.f,0.f,0.f,0.f}, acc3 = {0.f,0.f,0.f,0.f};
    float zl = 0.f, dl = 0.f;

    // named register queues, depth 2 (static indexing only — no scratch)
    int4 aq00, aq01, aq10, aq11;
    int4 gr00, gr01, gr02, gr03, gr10, gr11, gr12, gr13;

#define ISSUE(S, KC) do {                                                   \
        const int* _a = ap + (KC) * 32;                                     \
        aq##S##0 = *(const int4*)(_a);                                      \
        aq##S##1 = *(const int4*)(_a + 4);                                  \
        const ushort_t* _g = gb + (size_t)(KC) * 4096;                      \
        gr##S##0 = *(const int4*)(_g);                                      \
        gr##S##1 = *(const int4*)(_g + 512);                                \
        gr##S##2 = *(const int4*)(_g + 1024);                               \
        gr##S##3 = *(const int4*)(_g + 1536);                               \
    } while (0)

#define CONSUME(S, K) do {                                                  \
        float4 ev0 = *(const float4*)(&e2S[(K) * 32 + 8 * hh]);             \
        float4 ev1 = *(const float4*)(&e2S[(K) * 32 + 8 * hh + 4]);         \
        float ex[8] = {ev0.x, ev0.y, ev0.z, ev0.w,                          \
                       ev1.x, ev1.y, ev1.z, ev1.w};                         \
        int   ax[8] = {(aq##S##0).x, (aq##S##0).y, (aq##S##0).z,            \
                       (aq##S##0).w, (aq##S##1).x, (aq##S##1).y,            \
                       (aq##S##1).z, (aq##S##1).w};                         \
        bf16x8 af;                                                          \
        _Pragma("unroll")                                                   \
        for (int jj = 0; jj < 8; jj++) {                                    \
            float sp = e1f + ex[jj];                                        \
            float lk = fmaxf(sp, 0.2f * sp);                                \
            float sel = (ax[jj] > 0) ? KEXP : 0.f;                          \
            float wv = sel * __builtin_amdgcn_exp2f(lk);                    \
            zl += wv;                                                       \
            dl += sel;                                                      \
            af[jj] = (__bf16)wv;                                            \
        }                                                                   \
        acc0 = __builtin_amdgcn_mfma_f32_16x16x32_bf16(                     \
                   af, __builtin_bit_cast(bf16x8, gr##S##0), acc0, 0, 0, 0);\
        acc1 = __builtin_amdgcn_mfma_f32_16x16x32_bf16(                     \
                   af, __builtin_bit_cast(bf16x8, gr##S##1), acc1, 0, 0, 0);\
        acc2 = __builtin_amdgcn_mfma_f32_16x16x32_bf16(                     \
                   af, __builtin_bit_cast(bf16x8, gr##S##2), acc2, 0, 0, 0);\
        acc3 = __builtin_amdgcn_mfma_f32_16x16x32_bf16(                     \
                   af, __builtin_bit_cast(bf16x8, gr##S##3), acc3, 0, 0, 0);\
    } while (0)

#define STEP(S, K) do {                                                     \
        asm volatile("s_waitcnt vmcnt(6)");                                 \
        __builtin_amdgcn_sched_barrier(0);                                  \
        CONSUME(S, K);                                                      \
        int _kc = ((K) + 2 < 32) ? (K) + 2 : 31;                            \
        ISSUE(S, _kc);                                                      \
        __builtin_amdgcn_sched_barrier(0);                                  \
    } while (0)

    // prologue: two ordered regions of 6 VMEM ops each
    ISSUE(0, 0);
    __builtin_amdgcn_sched_barrier(0);
    ISSUE(1, 1);
    __builtin_amdgcn_sched_barrier(0);

    for (int k = 0; k < 32; k += 2) {
        STEP(0, k);
        STEP(1, k + 1);
    }

    // per-row Z, deg: lanes sharing rlo hold partials -> reduce lane bits 4,5
    zl += __shfl_xor(zl, 16); zl += __shfl_xor(zl, 32);
    dl += __shfl_xor(dl, 16); dl += __shfl_xor(dl, 32);
    float sc = (dl > 0.f) ? (dl * KEXPINV) / zl : 0.f;   // = deg / Z

    float scr[4];
    #pragma unroll
    for (int rg = 0; rg < 4; rg++) scr[rg] = __shfl(sc, 4 * hh + rg);

    // C layout: col = rlo, row(within frag) = 4*hh + rg
    float* ob = out + ((size_t)(b * NN + n0 + wr * 16)) * DD + wd * 64 + rlo;
    f32x4 accA[4] = {acc0, acc1, acc2, acc3};
    #pragma unroll
    for (int j = 0; j < 4; j++)
        #pragma unroll
        for (int rg = 0; rg < 4; rg++)
            ob[(size_t)(4 * hh + rg) * DD + j * 16] = accA[j][rg] * scr[rg];

#undef STEP
#undef CONSUME
#undef ISSUE
}

extern "C" void kernel_launch(void* const* d_in, const int* in_sizes, int n_in,
                              void* d_out, int out_size, void* d_ws, size_t ws_size,
                              hipStream_t stream) {
    const float* h   = (const float*)d_in[0];
    const float* g   = (const float*)d_in[1];
    const int*   adj = (const int*)d_in[2];
    const float* a1  = (const float*)d_in[3];
    const float* a2  = (const float*)d_in[4];
    float* out = (float*)d_out;

    // workspace: e1 @0 (128 KB), e2 @128 KB (128 KB), gq @512 KB (8 MB)
    char* ws = (char*)d_ws;
    float*    e1 = (float*)(ws);
    float*    e2 = (float*)(ws + (128u << 10));
    ushort_t* gq = (ushort_t*)(ws + (512u << 10));

    prep<<<dim3(MM / 64, BB), 256, 0, stream>>>(g, h, a1, a2, gq, e1, e2);
    attn_fused<<<dim3(NN / 32, BB), 256, 0, stream>>>(adj, gq, e1, e2, out);
}

// Round 12
// 51.914 us; speedup vs baseline: 1.5013x; 1.5013x over previous
//
#include <hip/hip_runtime.h>

#define BB 32
#define NN 1024
#define MM 1024
#define DD 128

typedef __attribute__((ext_vector_type(4))) float f32x4;
typedef __attribute__((ext_vector_type(8))) __bf16 bf16x8;
typedef unsigned short ushort_t;
typedef unsigned int uint_t;

#define L2E 1.44269504f
#define KEXP 9.357623e-14f      // exp(-30): folded softmax shift
#define KEXPINV 1.0686475e13f   // exp(+30)

__device__ __forceinline__ unsigned f2bf(float x) {
    unsigned u = __builtin_bit_cast(unsigned, x);
    return (u + 0x7fffu + ((u >> 16) & 1u)) >> 16;  // RNE bf16, finite inputs
}

// async global->LDS, 16 B per lane; dest must be linear (base + lane*16)
#define GLOAD16(gp, lp)                                                     \
    __builtin_amdgcn_global_load_lds(                                       \
        (const __attribute__((address_space(1))) unsigned int*)(gp),        \
        (__attribute__((address_space(3))) unsigned int*)(lp), 16, 0, 0)

// ---- Kernel 1 (prep): gq = bf16(g)^T tiles ; e2 = g·a2 ; e1 = h·a1 ----------
__global__ __launch_bounds__(256) void prep(
    const float* __restrict__ g, const float* __restrict__ h,
    const float* __restrict__ a1, const float* __restrict__ a2,
    ushort_t* __restrict__ gq, float* __restrict__ e1, float* __restrict__ e2)
{
    __shared__ ushort_t tl[DD][66];  // +2 pad breaks write bank conflicts
    int b = blockIdx.y, m0 = blockIdx.x * 64, t = threadIdx.x;

    #pragma unroll
    for (int i = 0; i < 8; i++) {
        int idx = i * 256 + t;
        int m = idx >> 5;            // 32 consecutive lanes share row m
        int c4 = (idx & 31) * 4;
        float4 v = *(const float4*)(h + ((size_t)(b * NN + m0 + m)) * DD + c4);
        float4 av = *(const float4*)(a1 + c4);
        float p = v.x * av.x + v.y * av.y + v.z * av.z + v.w * av.w;
        #pragma unroll
        for (int s = 16; s; s >>= 1) p += __shfl_xor(p, s);
        if ((t & 31) == 0) e1[b * NN + m0 + m] = p;
    }
    #pragma unroll
    for (int i = 0; i < 8; i++) {
        int idx = i * 256 + t;
        int m = idx >> 5;
        int c4 = (idx & 31) * 4;
        float4 v = *(const float4*)(g + ((size_t)(b * MM + m0 + m)) * DD + c4);
        tl[c4 + 0][m] = (ushort_t)f2bf(v.x);
        tl[c4 + 1][m] = (ushort_t)f2bf(v.y);
        tl[c4 + 2][m] = (ushort_t)f2bf(v.z);
        tl[c4 + 3][m] = (ushort_t)f2bf(v.w);
        float4 av = *(const float4*)(a2 + c4);
        float p = v.x * av.x + v.y * av.y + v.z * av.z + v.w * av.w;
        #pragma unroll
        for (int s = 16; s; s >>= 1) p += __shfl_xor(p, s);
        if ((t & 31) == 0) e2[b * MM + m0 + m] = p;
    }
    __syncthreads();
    #pragma unroll
    for (int i = 0; i < 4; i++) {
        int idx = i * 256 + t;
        int d = idx >> 3;            // 0..127
        int c = (idx & 7) * 8;       // local m group
        int4 o;
        o.x = (int)((unsigned)tl[d][c + 0] | ((unsigned)tl[d][c + 1] << 16));
        o.y = (int)((unsigned)tl[d][c + 2] | ((unsigned)tl[d][c + 3] << 16));
        o.z = (int)((unsigned)tl[d][c + 4] | ((unsigned)tl[d][c + 5] << 16));
        o.w = (int)((unsigned)tl[d][c + 6] | ((unsigned)tl[d][c + 7] << 16));
        int mg = m0 + c;
        *(int4*)(gq + (((size_t)((b * 32 + (mg >> 5)) * DD + d)) << 5) + (mg & 31)) = o;
    }
}

// ---- Kernel 2: fused adj-stream + softmax + PV via LDS double-buffer --------
// block = 4 waves x 16 rows = 64 rows, all 128 d. Per chunk (32 m):
// stage adj(8KB,src-swizzled)+gq(8KB) into LDS[buf^1] with global_load_lds
// (compiler can't sink DMA), compute chunk from LDS[buf], vmcnt(0)+barrier.
__global__ __launch_bounds__(256) void attn_tiled(
    const int* __restrict__ adj, const ushort_t* __restrict__ gq,
    const float* __restrict__ e1, const float* __restrict__ e2,
    float* __restrict__ out)
{
    __shared__ __align__(16) float e2S[MM];            // 4 KB
    __shared__ __align__(16) int adjS[2][64 * 32];     // 2 x 8 KB
    __shared__ __align__(16) ushort_t gqS[2][32 * 128];// 2 x 8 KB

    int b = blockIdx.y, n0 = blockIdx.x * 64, t = threadIdx.x;
    int wid = t >> 6, lane = t & 63;
    int rlo = lane & 15, hh = lane >> 4;
    int r = wid * 16 + rlo;          // block-local row 0..63
    int r8 = r & 7;

    // stage e2 (scaled to log2 domain)
    {
        float4 ev = *(const float4*)(e2 + b * MM + t * 4);
        ev.x *= L2E; ev.y *= L2E; ev.z *= L2E; ev.w *= L2E;
        *(float4*)(&e2S[t * 4]) = ev;
    }
    float e1f = L2E * e1[b * NN + n0 + r];

    const int* adjb = adj + (size_t)(b * NN + n0) * MM;
    const ushort_t* gqb = gq + (size_t)b * (32 * DD * 32);

    // staging indices: di in {t, t+256} covers 512 x 16B slots
    int di0 = t, di1 = t + 256;
    int row0 = di0 >> 3, slot0 = di0 & 7, seg0 = slot0 ^ (row0 & 7);
    int row1 = di1 >> 3, slot1 = di1 & 7, seg1 = slot1 ^ (row1 & 7);

#define STAGE(P, K) do {                                                    \
        GLOAD16(adjb + (size_t)row0 * MM + (K) * 32 + seg0 * 4,             \
                &adjS[P][di0 * 4]);                                         \
        GLOAD16(adjb + (size_t)row1 * MM + (K) * 32 + seg1 * 4,             \
                &adjS[P][di1 * 4]);                                         \
        GLOAD16(gqb + (size_t)(K) * 4096 + di0 * 8, &gqS[P][di0 * 8]);      \
        GLOAD16(gqb + (size_t)(K) * 4096 + di1 * 8, &gqS[P][di1 * 8]);      \
    } while (0)

    f32x4 acc[8];
    #pragma unroll
    for (int j = 0; j < 8; j++) acc[j] = (f32x4){0.f, 0.f, 0.f, 0.f};
    float zl = 0.f, dl = 0.f;

    STAGE(0, 0);
    asm volatile("s_waitcnt vmcnt(0)");
    __syncthreads();

    for (int k = 0; k < 32; ++k) {
        int p = k & 1;
        if (k < 31) STAGE(p ^ 1, k + 1);

        // A-side: my 8 adj words (swizzled slots), e2 slice
        int4 a0 = *(const int4*)(&adjS[p][r * 32 + ((2 * hh) ^ r8) * 4]);
        int4 a1 = *(const int4*)(&adjS[p][r * 32 + ((2 * hh + 1) ^ r8) * 4]);
        float4 ev0 = *(const float4*)(&e2S[k * 32 + 8 * hh]);
        float4 ev1 = *(const float4*)(&e2S[k * 32 + 8 * hh + 4]);
        float ex[8] = {ev0.x, ev0.y, ev0.z, ev0.w, ev1.x, ev1.y, ev1.z, ev1.w};
        int   ax[8] = {a0.x, a0.y, a0.z, a0.w, a1.x, a1.y, a1.z, a1.w};

        bf16x8 af;
        #pragma unroll
        for (int jj = 0; jj < 8; jj++) {
            float sp = e1f + ex[jj];              // log2-domain score
            float lk = fmaxf(sp, 0.2f * sp);      // leaky (pos-homogeneous)
            float sel = (ax[jj] > 0) ? KEXP : 0.f;
            float wv = sel * __builtin_amdgcn_exp2f(lk);
            zl += wv;
            dl += sel;
            af[jj] = (__bf16)wv;
        }
        // B-side: 8 d-fragments from LDS gq tile [d][m]
        #pragma unroll
        for (int j = 0; j < 8; j++) {
            int4 bv = *(const int4*)(&gqS[p][(j * 16 + rlo) * 32 + 8 * hh]);
            acc[j] = __builtin_amdgcn_mfma_f32_16x16x32_bf16(
                         af, __builtin_bit_cast(bf16x8, bv), acc[j], 0, 0, 0);
        }

        asm volatile("s_waitcnt vmcnt(0)");
        __syncthreads();
    }
#undef STAGE

    // per-row Z, deg: lanes sharing rlo hold partials -> reduce lane bits 4,5
    zl += __shfl_xor(zl, 16); zl += __shfl_xor(zl, 32);
    dl += __shfl_xor(dl, 16); dl += __shfl_xor(dl, 32);
    float sc = (dl > 0.f) ? (dl * KEXPINV) / zl : 0.f;   // = deg / Z

    float scr[4];
    #pragma unroll
    for (int rg = 0; rg < 4; rg++) scr[rg] = __shfl(sc, 4 * hh + rg);

    // C layout: col = rlo, row(within frag) = 4*hh + rg
    float* ob = out + ((size_t)(b * NN + n0 + wid * 16)) * DD + rlo;
    #pragma unroll
    for (int j = 0; j < 8; j++)
        #pragma unroll
        for (int rg = 0; rg < 4; rg++)
            ob[(size_t)(4 * hh + rg) * DD + j * 16] = acc[j][rg] * scr[rg];
}

extern "C" void kernel_launch(void* const* d_in, const int* in_sizes, int n_in,
                              void* d_out, int out_size, void* d_ws, size_t ws_size,
                              hipStream_t stream) {
    const float* h   = (const float*)d_in[0];
    const float* g   = (const float*)d_in[1];
    const int*   adj = (const int*)d_in[2];
    const float* a1  = (const float*)d_in[3];
    const float* a2  = (const float*)d_in[4];
    float* out = (float*)d_out;

    // workspace: e1 @0 (128 KB), e2 @128 KB (128 KB), gq @512 KB (8 MB)
    char* ws = (char*)d_ws;
    float*    e1 = (float*)(ws);
    float*    e2 = (float*)(ws + (128u << 10));
    ushort_t* gq = (ushort_t*)(ws + (512u << 10));

    prep<<<dim3(MM / 64, BB), 256, 0, stream>>>(g, h, a1, a2, gq, e1, e2);
    attn_tiled<<<dim3(NN / 64, BB), 256, 0, stream>>>(adj, gq, e1, e2, out);
}

// Round 13
// 48.090 us; speedup vs baseline: 1.6206x; 1.0795x over previous
//
#include <hip/hip_runtime.h>

#define BB 32
#define NN 1024
#define MM 1024
#define DD 128

typedef __attribute__((ext_vector_type(4))) float f32x4;
typedef __attribute__((ext_vector_type(8))) __bf16 bf16x8;
typedef unsigned short ushort_t;
typedef unsigned int uint_t;

#define L2E 1.44269504f
#define KEXP 9.357623e-14f      // exp(-30): folded softmax shift
#define KEXPINV 1.0686475e13f   // exp(+30)

__device__ __forceinline__ unsigned f2bf(float x) {
    unsigned u = __builtin_bit_cast(unsigned, x);
    return (u + 0x7fffu + ((u >> 16) & 1u)) >> 16;  // RNE bf16, finite inputs
}

// async global->LDS, 16 B per lane; dest must be linear (base + lane*16)
#define GLOAD16(gp, lp)                                                     \
    __builtin_amdgcn_global_load_lds(                                       \
        (const __attribute__((address_space(1))) unsigned int*)(gp),        \
        (__attribute__((address_space(3))) unsigned int*)(lp), 16, 0, 0)

// ---- Kernel 1 (prep): gq = bf16(g)^T tiles ; e2 = g·a2 ; e1 = h·a1 ----------
__global__ __launch_bounds__(256) void prep(
    const float* __restrict__ g, const float* __restrict__ h,
    const float* __restrict__ a1, const float* __restrict__ a2,
    ushort_t* __restrict__ gq, float* __restrict__ e1, float* __restrict__ e2)
{
    __shared__ ushort_t tl[DD][66];  // +2 pad breaks write bank conflicts
    int b = blockIdx.y, m0 = blockIdx.x * 64, t = threadIdx.x;

    #pragma unroll
    for (int i = 0; i < 8; i++) {
        int idx = i * 256 + t;
        int m = idx >> 5;            // 32 consecutive lanes share row m
        int c4 = (idx & 31) * 4;
        float4 v = *(const float4*)(h + ((size_t)(b * NN + m0 + m)) * DD + c4);
        float4 av = *(const float4*)(a1 + c4);
        float p = v.x * av.x + v.y * av.y + v.z * av.z + v.w * av.w;
        #pragma unroll
        for (int s = 16; s; s >>= 1) p += __shfl_xor(p, s);
        if ((t & 31) == 0) e1[b * NN + m0 + m] = p;
    }
    #pragma unroll
    for (int i = 0; i < 8; i++) {
        int idx = i * 256 + t;
        int m = idx >> 5;
        int c4 = (idx & 31) * 4;
        float4 v = *(const float4*)(g + ((size_t)(b * MM + m0 + m)) * DD + c4);
        tl[c4 + 0][m] = (ushort_t)f2bf(v.x);
        tl[c4 + 1][m] = (ushort_t)f2bf(v.y);
        tl[c4 + 2][m] = (ushort_t)f2bf(v.z);
        tl[c4 + 3][m] = (ushort_t)f2bf(v.w);
        float4 av = *(const float4*)(a2 + c4);
        float p = v.x * av.x + v.y * av.y + v.z * av.z + v.w * av.w;
        #pragma unroll
        for (int s = 16; s; s >>= 1) p += __shfl_xor(p, s);
        if ((t & 31) == 0) e2[b * MM + m0 + m] = p;
    }
    __syncthreads();
    #pragma unroll
    for (int i = 0; i < 4; i++) {
        int idx = i * 256 + t;
        int d = idx >> 3;            // 0..127
        int c = (idx & 7) * 8;       // local m group
        int4 o;
        o.x = (int)((unsigned)tl[d][c + 0] | ((unsigned)tl[d][c + 1] << 16));
        o.y = (int)((unsigned)tl[d][c + 2] | ((unsigned)tl[d][c + 3] << 16));
        o.z = (int)((unsigned)tl[d][c + 4] | ((unsigned)tl[d][c + 5] << 16));
        o.w = (int)((unsigned)tl[d][c + 6] | ((unsigned)tl[d][c + 7] << 16));
        int mg = m0 + c;
        *(int4*)(gq + (((size_t)((b * 32 + (mg >> 5)) * DD + d)) << 5) + (mg & 31)) = o;
    }
}

// ---- Kernel 2: fused adj+softmax+PV, 4-deep LDS ring, counted vmcnt ---------
// block = 4 waves x 16 rows = 64 rows, all 128 d. Per chunk (32 m): raw
// s_barrier + vmcnt(8) keeps stages k+1,k+2 in flight across the barrier
// (3 compute phases of latency cover). Stage k+3 issued after the barrier
// that retires all reads of buffer (k+3)&3 = (k-1)&3.
__global__ __launch_bounds__(256, 2) void attn_tiled(
    const int* __restrict__ adj, const ushort_t* __restrict__ gq,
    const float* __restrict__ e1, const float* __restrict__ e2,
    float* __restrict__ out)
{
    __shared__ __align__(16) float e2S[MM];             // 4 KB
    __shared__ __align__(16) int adjS[4][64 * 32];      // 4 x 8 KB
    __shared__ __align__(16) ushort_t gqS[4][128 * 32]; // 4 x 8 KB

    int b = blockIdx.y, n0 = blockIdx.x * 64, t = threadIdx.x;
    int wid = t >> 6, lane = t & 63;
    int rlo = lane & 15, hh = lane >> 4;
    int r = wid * 16 + rlo;          // block-local row 0..63
    int r8 = r & 7;

    // stage e2 (scaled to log2 domain)
    {
        float4 ev = *(const float4*)(e2 + b * MM + t * 4);
        ev.x *= L2E; ev.y *= L2E; ev.z *= L2E; ev.w *= L2E;
        *(float4*)(&e2S[t * 4]) = ev;
    }
    float e1f = L2E * e1[b * NN + n0 + r];
    __syncthreads();                 // e2S ready (no DMA in flight yet)

    const int* adjb = adj + (size_t)(b * NN + n0) * MM;
    const ushort_t* gqb = gq + (size_t)b * (32 * DD * 32);

    // adj staging: di in {t, t+256} covers 512 x 16B slots (64 rows x 8 slots),
    // source-swizzled seg = slot ^ (row&7)
    int adi0 = t, adi1 = t + 256;
    int arow0 = adi0 >> 3, aseg0 = (adi0 & 7) ^ (arow0 & 7);
    int arow1 = adi1 >> 3, aseg1 = (adi1 & 7) ^ (arow1 & 7);
    // gq staging: 512 slots = 128 d-rows x 4 slots of 8 shorts,
    // source-swizzled seg = slot ^ ((d>>1)&3)
    int gd0 = adi0 >> 2, gseg0 = (adi0 & 3) ^ ((gd0 >> 1) & 3);
    int gd1 = adi1 >> 2, gseg1 = (adi1 & 3) ^ ((gd1 >> 1) & 3);

#define STAGE(P, K) do {                                                    \
        GLOAD16(adjb + (size_t)arow0 * MM + (K) * 32 + aseg0 * 4,           \
                &adjS[P][adi0 * 4]);                                        \
        GLOAD16(adjb + (size_t)arow1 * MM + (K) * 32 + aseg1 * 4,           \
                &adjS[P][adi1 * 4]);                                        \
        GLOAD16(gqb + (size_t)(K) * 4096 + gd0 * 32 + gseg0 * 8,            \
                &gqS[P][adi0 * 8]);                                         \
        GLOAD16(gqb + (size_t)(K) * 4096 + gd1 * 32 + gseg1 * 8,            \
                &gqS[P][adi1 * 8]);                                         \
    } while (0)

    f32x4 acc[8];
    #pragma unroll
    for (int j = 0; j < 8; j++) acc[j] = (f32x4){0.f, 0.f, 0.f, 0.f};
    float zl = 0.f, dl = 0.f;

#define COMPUTE(P, K) do {                                                  \
        int4 a0 = *(const int4*)(&adjS[P][r * 32 + ((2 * hh) ^ r8) * 4]);   \
        int4 a1 = *(const int4*)(&adjS[P][r * 32 + ((2 * hh + 1) ^ r8) * 4]);\
        float4 ev0 = *(const float4*)(&e2S[(K) * 32 + 8 * hh]);             \
        float4 ev1 = *(const float4*)(&e2S[(K) * 32 + 8 * hh + 4]);         \
        float ex[8] = {ev0.x, ev0.y, ev0.z, ev0.w,                          \
                       ev1.x, ev1.y, ev1.z, ev1.w};                         \
        int   ax[8] = {a0.x, a0.y, a0.z, a0.w, a1.x, a1.y, a1.z, a1.w};     \
        bf16x8 af;                                                          \
        _Pragma("unroll")                                                   \
        for (int jj = 0; jj < 8; jj++) {                                    \
            float sp = e1f + ex[jj];                                        \
            float lk = fmaxf(sp, 0.2f * sp);                                \
            float sel = (ax[jj] > 0) ? KEXP : 0.f;                          \
            float wv = sel * __builtin_amdgcn_exp2f(lk);                    \
            zl += wv;                                                       \
            dl += sel;                                                      \
            af[jj] = (__bf16)wv;                                            \
        }                                                                   \
        _Pragma("unroll")                                                   \
        for (int j = 0; j < 8; j++) {                                       \
            int d = j * 16 + rlo;                                           \
            int4 bv = *(const int4*)(                                       \
                &gqS[P][d * 32 + (hh ^ ((rlo >> 1) & 3)) * 8]);             \
            acc[j] = __builtin_amdgcn_mfma_f32_16x16x32_bf16(               \
                         af, __builtin_bit_cast(bf16x8, bv), acc[j], 0,0,0);\
        }                                                                   \
    } while (0)

    // prologue: 3 stages in flight (12 DMA ops/thread)
    STAGE(0, 0); STAGE(1, 1); STAGE(2, 2);

    for (int k = 0; k < 30; ++k) {
        asm volatile("s_waitcnt vmcnt(8)" ::: "memory");  // stage k landed
        __builtin_amdgcn_s_barrier();                     // raw: no drain
        __builtin_amdgcn_sched_barrier(0);
        if (k < 29) STAGE((k + 3) & 3, k + 3);            // overwrites (k-1)&3
        COMPUTE(k & 3, k);
    }
    asm volatile("s_waitcnt vmcnt(4)" ::: "memory");      // stage 30 landed
    __builtin_amdgcn_s_barrier();
    __builtin_amdgcn_sched_barrier(0);
    COMPUTE(2, 30);
    asm volatile("s_waitcnt vmcnt(0)" ::: "memory");      // stage 31 landed
    __builtin_amdgcn_s_barrier();
    __builtin_amdgcn_sched_barrier(0);
    COMPUTE(3, 31);

#undef COMPUTE
#undef STAGE

    // per-row Z, deg: lanes sharing rlo hold partials -> reduce lane bits 4,5
    zl += __shfl_xor(zl, 16); zl += __shfl_xor(zl, 32);
    dl += __shfl_xor(dl, 16); dl += __shfl_xor(dl, 32);
    float sc = (dl > 0.f) ? (dl * KEXPINV) / zl : 0.f;   // = deg / Z

    float scr[4];
    #pragma unroll
    for (int rg = 0; rg < 4; rg++) scr[rg] = __shfl(sc, 4 * hh + rg);

    // C layout: col = rlo, row(within frag) = 4*hh + rg
    float* ob = out + ((size_t)(b * NN + n0 + wid * 16)) * DD + rlo;
    #pragma unroll
    for (int j = 0; j < 8; j++)
        #pragma unroll
        for (int rg = 0; rg < 4; rg++)
            ob[(size_t)(4 * hh + rg) * DD + j * 16] = acc[j][rg] * scr[rg];
}

extern "C" void kernel_launch(void* const* d_in, const int* in_sizes, int n_in,
                              void* d_out, int out_size, void* d_ws, size_t ws_size,
                              hipStream_t stream) {
    const float* h   = (const float*)d_in[0];
    const float* g   = (const float*)d_in[1];
    const int*   adj = (const int*)d_in[2];
    const float* a1  = (const float*)d_in[3];
    const float* a2  = (const float*)d_in[4];
    float* out = (float*)d_out;

    // workspace: e1 @0 (128 KB), e2 @128 KB (128 KB), gq @512 KB (8 MB)
    char* ws = (char*)d_ws;
    float*    e1 = (float*)(ws);
    float*    e2 = (float*)(ws + (128u << 10));
    ushort_t* gq = (ushort_t*)(ws + (512u << 10));

    prep<<<dim3(MM / 64, BB), 256, 0, stream>>>(g, h, a1, a2, gq, e1, e2);
    attn_tiled<<<dim3(NN / 64, BB), 256, 0, stream>>>(adj, gq, e1, e2, out);
}